// Round 20
// baseline (672.988 us; speedup 1.0000x reference)
//
#include <hip/hip_runtime.h>
#include <stdint.h>

// ---- Problem constants -------------------------------------------------
#define DIM   1536
#define NQ    6272      // 8 * 28 * 28 queries
#define NQP   6400      // padded to 50 * 128
#define NB    50000     // bank rows
#define NBP2  50176     // padded to 196 * 256
#define MT3   50
#define NT3   196
#define GRID3 (MT3 * NT3)   // 9800
#define NPIX  (8 * 224 * 224)

typedef float f32x4 __attribute__((ext_vector_type(4)));
typedef int   i32x4 __attribute__((ext_vector_type(4)));
typedef __attribute__((address_space(3))) signed char lds_i8;

__device__ inline void gll16(const signed char* g, signed char* l) {
  __builtin_amdgcn_global_load_lds(
      (const __attribute__((address_space(1))) uint32_t*)g,
      (__attribute__((address_space(3))) uint32_t*)l, 16, 0, 0);
}

// ---- init: minbits = +inf, image scores = 0 ---------------------------
__global__ void init_kernel(uint32_t* __restrict__ minbits, float* __restrict__ out_scores) {
  int i = blockIdx.x * 256 + threadIdx.x;
  if (i < NQP) minbits[i] = 0x7F800000u;   // +inf
  if (i < 8)   out_scores[i] = 0.0f;
}

// ---- fp32 -> int8 row quantization + fp32 row norms + scales ----------
__global__ void quant_rows(const float* __restrict__ src, signed char* __restrict__ dst,
                           float* __restrict__ norms, float* __restrict__ scales,
                           int nsrc, int ndst) {
  int row  = blockIdx.x * 4 + (threadIdx.x >> 6);
  int lane = threadIdx.x & 63;
  if (row >= ndst) return;
  uint32_t* drow = (uint32_t*)(dst + (size_t)row * DIM);
  if (row < nsrc) {
    const float4* s = (const float4*)(src + (size_t)row * DIM);
    float4 v[6]; float ns = 0.f, mx = 0.f;
#pragma unroll
    for (int i = 0; i < 6; ++i) {
      v[i] = s[lane + 64 * i];
      ns += v[i].x * v[i].x + v[i].y * v[i].y + v[i].z * v[i].z + v[i].w * v[i].w;
      mx = fmaxf(mx, fmaxf(fmaxf(fabsf(v[i].x), fabsf(v[i].y)),
                           fmaxf(fabsf(v[i].z), fabsf(v[i].w))));
    }
#pragma unroll
    for (int off = 32; off >= 1; off >>= 1) {
      ns += __shfl_xor(ns, off);
      mx = fmaxf(mx, __shfl_xor(mx, off));
    }
    float inv = (mx > 0.f) ? 127.0f / mx : 0.f;
#pragma unroll
    for (int i = 0; i < 6; ++i) {
      int a = max(-127, min(127, __float2int_rn(v[i].x * inv)));
      int b = max(-127, min(127, __float2int_rn(v[i].y * inv)));
      int c = max(-127, min(127, __float2int_rn(v[i].z * inv)));
      int d = max(-127, min(127, __float2int_rn(v[i].w * inv)));
      drow[lane + 64 * i] = (uint32_t)(a & 255) | ((uint32_t)(b & 255) << 8) |
                            ((uint32_t)(c & 255) << 16) | ((uint32_t)(d & 255) << 24);
    }
    if (lane == 0) { norms[row] = ns; scales[row] = mx * (1.0f / 127.0f); }
  } else {
#pragma unroll
    for (int i = 0; i < 6; ++i) drow[lane + 64 * i] = 0u;
    if (lane == 0) { norms[row] = 1e30f; scales[row] = 0.f; }   // pad never wins
  }
}

// ---- fused 128x256 int8 GEMM + column-min, 2 blocks/CU ----------------
// BM=128, BN=256, 512 thr = 8 waves (2M x 4N), per-wave 64x64 out.
// R19 base (2 blocks/CU, 3-buffer LDS rotation, chunk-XOR swizzle) with
// ONE phase per tile (16 MFMA): 24 barriers/block instead of 48. The R17
// barrier-merge failed on 2 buffers (forced VM0/iter); 3 buffers keep the
// gate COUNTED (VM3) at every phase. Ledger: stage(u+2) -> buf(u-1)%3,
// readers drained at phase u-1's LGKM0 + BAR; VM3 at phase u retires
// stage(u+1), keeps stage(u+2) (2-phase flight); BAR publishes buf(u+1).
#define BAR   do { asm volatile("s_barrier" ::: "memory"); \
                   __builtin_amdgcn_sched_barrier(0); } while(0)
#define LGKM0 do { asm volatile("s_waitcnt lgkmcnt(0)" ::: "memory"); \
                   __builtin_amdgcn_sched_barrier(0); } while(0)
#define VM0   asm volatile("s_waitcnt vmcnt(0)" ::: "memory")
#define VM3   asm volatile("s_waitcnt vmcnt(3)" ::: "memory")
#define NOGATE
#define PHI   __builtin_amdgcn_s_setprio(1)
#define PLO   __builtin_amdgcn_s_setprio(0)

#define DSR(dst, base, imm) \
  asm volatile("ds_read_b128 %0, %1 offset:%2" : "=v"(dst) : "v"(base), "i"(imm))

// 16 MFMA: 4 m-frags x 4 n-frags, K=64
#define MFMA16 do { \
  _Pragma("unroll") for (int m_ = 0; m_ < 4; ++m_) \
  _Pragma("unroll") for (int n_ = 0; n_ < 4; ++n_) \
    acc[m_][n_] = __builtin_amdgcn_mfma_i32_16x16x64_i8( \
      __builtin_bit_cast(i32x4, a[m_]), __builtin_bit_cast(i32x4, b[n_]), \
      acc[m_][n_], 0, 0, 0); \
} while(0)

// stage tile -> buf: A 128x64 (1 gll16), B 256x64 (2 gll16); dest linear,
// source row = tid>>2 (coalesced 64B segs), chunk (tid&3)^((tid>>3)&3).
#define STAGE_AB(sb, ktc) do { \
  gll16(gA + gOffA + (ktc), &sA[sb][sdst]); \
  const signed char* _g = gB + gOffA + (ktc); \
  gll16(_g,                      &sB[sb][sdst]); \
  gll16(_g + (size_t)128 * DIM,  &sB[sb][8192 + sdst]); \
} while(0)

// one tile phase: 8 reads; drain; optional stage(u+2); gate; BAR; 16 MFMA
#define PH(buf, SN, sb, ktc, GATE) do { \
  DSR(a[0], aOff, (buf) * 8192 + 0);    DSR(a[1], aOff, (buf) * 8192 + 1024); \
  DSR(a[2], aOff, (buf) * 8192 + 2048); DSR(a[3], aOff, (buf) * 8192 + 3072); \
  DSR(b[0], bOff, (buf) * 16384 + 0);    DSR(b[1], bOff, (buf) * 16384 + 1024); \
  DSR(b[2], bOff, (buf) * 16384 + 2048); DSR(b[3], bOff, (buf) * 16384 + 3072); \
  LGKM0; \
  if (SN) STAGE_AB(sb, ktc); \
  GATE; BAR; PHI; MFMA16; PLO; \
} while(0)

__global__ __launch_bounds__(512, 4)
void gemm_min8(const signed char* __restrict__ fA, const signed char* __restrict__ bB,
               const float* __restrict__ bn, const float* __restrict__ bscale,
               const float* __restrict__ qscale, uint32_t* __restrict__ minbits) {
  __shared__ __align__(16) signed char sA[3][8192];    // 24 KiB
  __shared__ __align__(16) signed char sB[3][16384];   // 48 KiB

  const int nwg = GRID3;
  int bid = blockIdx.x;
  const int qch = nwg >> 3, rch = nwg & 7;
  int xcd = bid & 7, loc = bid >> 3;
  int swz = (xcd < rch ? xcd * (qch + 1) : rch * (qch + 1) + (xcd - rch) * qch) + loc;
  int mt = swz % MT3;            // M-fast: consecutive blocks share the B (bank) panel
  int nt = swz / MT3;

  int tid = threadIdx.x;
  int lane = tid & 63, wave = tid >> 6;
  int wm = wave >> 2, wn = wave & 3;
  int lr = lane & 15, k16 = lane >> 4;

  const signed char* gA = fA + (size_t)(mt * 128) * DIM;
  const signed char* gB = bB + (size_t)(nt * 256) * DIM;

  // staging: row = tid>>2 (A rows 0-127; B also +128), chunk xor-permuted
  size_t gOffA = (size_t)(tid >> 2) * DIM + ((tid & 3) ^ ((tid >> 3) & 3)) * 16;
  int sdst = tid * 16;

  // read bases: data (row, k16) at row*64 + (k16 ^ ((row>>1)&3))*16
  int cxA = (k16 ^ ((lr >> 1) & 3)) * 16;
  uint32_t aOff = (uint32_t)(uintptr_t)(lds_i8*)&sA[0][(wm * 64 + lr) * 64 + cxA];
  uint32_t bOff = (uint32_t)(uintptr_t)(lds_i8*)&sB[0][(wn * 64 + lr) * 64 + cxA];

  i32x4 acc[4][4] = {};
  f32x4 a[4], b[4];

  // prologue: stage tiles 0 (buf0) + 1 (buf1); VM3 retires t0's 3 gll16
  // (keeps t1's 3 in flight, retired at tile 0's VM3 gate); publish.
  STAGE_AB(0, 0);
  STAGE_AB(1, 64);
  VM3; BAR;

  // tiles 3j, 3j+1, 3j+2 in bufs 0,1,2; tile u stages tile u+2 (ktc=(u+2)*64)
#pragma unroll 1
  for (int j = 0; j < 7; ++j) {
    int kb = j * 192;
    PH(0, 1, 2, kb + 128, VM3);   // tile 3j
    PH(1, 1, 0, kb + 192, VM3);   // tile 3j+1
    PH(2, 1, 1, kb + 256, VM3);   // tile 3j+2
  }
  // tail: tile 21 (stages t23 -> buf2), tile 22 (VM0: t23 must land), tile 23
  PH(0, 1, 2, 1472, VM3);
  PH(1, 0, 0, 0, VM0);
  PH(2, 0, 0, 0, NOGATE);

  // epilogue: per-row min over this tile's 256 cols of (bn - 2*sq*sb*idot)
  float bnv[4], bsv[4];
#pragma unroll
  for (int n_ = 0; n_ < 4; ++n_) {
    int col = nt * 256 + wn * 64 + n_ * 16 + lr;
    bnv[n_] = bn[col];
    bsv[n_] = 2.0f * bscale[col];
  }
  int qbase = mt * 128 + wm * 64;
#pragma unroll
  for (int m_ = 0; m_ < 4; ++m_) {
    f32x4 sq = *(const f32x4*)&qscale[qbase + m_ * 16 + (lane >> 4) * 4];
#pragma unroll
    for (int r = 0; r < 4; ++r) {
      float sqr = sq[r];
      float v =          bnv[0] - bsv[0] * sqr * (float)acc[m_][0][r];
      v = fminf(v, bnv[1] - bsv[1] * sqr * (float)acc[m_][1][r]);
      v = fminf(v, bnv[2] - bsv[2] * sqr * (float)acc[m_][2][r]);
      v = fminf(v, bnv[3] - bsv[3] * sqr * (float)acc[m_][3][r]);
      // C/D layout (shape-determined): col = lane&15, row = (lane>>4)*4+r
      v = fminf(v, __shfl_xor(v, 1));
      v = fminf(v, __shfl_xor(v, 2));
      v = fminf(v, __shfl_xor(v, 4));
      v = fminf(v, __shfl_xor(v, 8));
      if (lr == 0) {
        int q = qbase + m_ * 16 + (lane >> 4) * 4 + r;
        atomicMin(&minbits[q], __float_as_uint(v));  // positive floats: uint order == float order
      }
    }
  }
}

// ---- patch scores + per-image max -------------------------------------
__global__ void scores_kernel(const uint32_t* __restrict__ minbits, const float* __restrict__ qn,
                              float* __restrict__ ps, float* __restrict__ img) {
  int q = blockIdx.x * 256 + threadIdx.x;
  if (q >= NQ) return;
  float s = __uint_as_float(minbits[q]) + qn[q];
  ps[q] = s;
  atomicMax((uint32_t*)&img[q / 784], __float_as_uint(s));  // scores > 0
}

// ---- bilinear 28x28 -> 224x224 (half-pixel centers, edge clamp) -------
__global__ void resize_kernel(const float* __restrict__ ps, float* __restrict__ masks) {
  int idx = blockIdx.x * 256 + threadIdx.x;
  if (idx >= NPIX) return;
  int b   = idx / (224 * 224);
  int rem = idx - b * (224 * 224);
  int oy  = rem / 224;
  int ox  = rem - oy * 224;
  float sy = (oy + 0.5f) * 0.125f - 0.5f;
  float sx = (ox + 0.5f) * 0.125f - 0.5f;
  float fy0 = floorf(sy), fx0 = floorf(sx);
  int y0 = (int)fy0, x0 = (int)fx0;
  float fy = sy - fy0, fx = sx - fx0;
  int y0c = min(max(y0, 0), 27),     y1c = min(max(y0 + 1, 0), 27);
  int x0c = min(max(x0, 0), 27),     x1c = min(max(x0 + 1, 0), 27);
  const float* p = ps + b * 784;
  float top = p[y0c * 28 + x0c] * (1.f - fx) + p[y0c * 28 + x1c] * fx;
  float bot = p[y1c * 28 + x0c] * (1.f - fx) + p[y1c * 28 + x1c] * fx;
  masks[idx] = top * (1.f - fy) + bot * fy;
}

// ---- host launch -------------------------------------------------------
extern "C" void kernel_launch(void* const* d_in, const int* in_sizes, int n_in,
                              void* d_out, int out_size, void* d_ws, size_t ws_size,
                              hipStream_t stream) {
  const float* features = (const float*)d_in[0];   // [6272, 1536]
  const float* bank     = (const float*)d_in[1];   // [50000, 1536]

  char* ws = (char*)d_ws;
  size_t off = 0;
  signed char* bankQ = (signed char*)(ws + off); off += (size_t)NBP2 * DIM;   // 77.1 MB
  signed char* featQ = (signed char*)(ws + off); off += (size_t)NQP * DIM;    //  9.8 MB
  float*    bn      = (float*)(ws + off);    off += (size_t)NBP2 * 4;
  float*    qn      = (float*)(ws + off);    off += (size_t)NQP * 4;
  float*    bscale  = (float*)(ws + off);    off += (size_t)NBP2 * 4;
  float*    qscale  = (float*)(ws + off);    off += (size_t)NQP * 4;
  uint32_t* minbits = (uint32_t*)(ws + off); off += (size_t)NQP * 4;
  float*    ps      = (float*)(ws + off);    off += (size_t)NQ * 4;

  float* out_scores = (float*)d_out;       // [8]
  float* masks      = out_scores + 8;      // [8,224,224]

  hipLaunchKernelGGL(init_kernel, dim3(25), dim3(256), 0, stream, minbits, out_scores);
  hipLaunchKernelGGL(quant_rows, dim3(NBP2 / 4), dim3(256), 0, stream, bank, bankQ, bn, bscale, NB, NBP2);
  hipLaunchKernelGGL(quant_rows, dim3(NQP / 4), dim3(256), 0, stream, features, featQ, qn, qscale, NQ, NQP);
  hipLaunchKernelGGL(gemm_min8, dim3(GRID3), dim3(512), 0, stream, featQ, bankQ, bn, bscale, qscale, minbits);
  hipLaunchKernelGGL(scores_kernel, dim3(25), dim3(256), 0, stream, minbits, qn, ps, out_scores);
  hipLaunchKernelGGL(resize_kernel, dim3((NPIX + 255) / 256), dim3(256), 0, stream, ps, masks);
}